// Round 1
// baseline (520.182 us; speedup 1.0000x reference)
//
#include <hip/hip_runtime.h>
#include <math.h>

// Problem constants (derived from the reference):
//   x: (8,4,2,2999,400) f32  ->  N=32 batches, C=2, F=2999, T=400
//   FC_INDEX = 1199 ; noise freqs: f < 999 || f >= 1400 (2598 rows)
#define N_BATCH 32
#define NF 2999
#define NT 400
#define NT4 100          // float4s per t-row
#define FC_IDX 1199
#define NOISE_LO 999     // f < NOISE_LO is noise
#define NOISE_HI 1400    // f >= NOISE_HI is noise
#define NOISE_F 2598
#define NOISE_CNT (NOISE_F * NT)   // 1039200 (mean divisor; mag already sums channels)
#define PLANE4 (NF * NT4)          // 299900 float4s per (n,c) plane

// ---------------- Kernel A: per-batch FC-row -> mid (argmax), sig (window sum);
// also zero the noise accumulators (runs before B on the same stream).
__global__ void kA_fcrow(const float* __restrict__ x, int* __restrict__ mid_out,
                         float* __restrict__ sig_out, float* __restrict__ noise_sum) {
    const int n = blockIdx.x;        // 0..31
    const int tid = threadIdx.x;     // 256 threads
    __shared__ float mag[NT];
    __shared__ float rv[256];
    __shared__ int   ri[256];

    const float* p0 = x + ((size_t)(n * 2 + 0) * NF + FC_IDX) * NT;
    const float* p1 = x + ((size_t)(n * 2 + 1) * NF + FC_IDX) * NT;
    for (int t = tid; t < NT; t += 256)
        mag[t] = fabsf(p0[t]) + fabsf(p1[t]);
    __syncthreads();

    // first-occurrence argmax (matches jnp.argmax tie-break)
    float bv = -1.0f; int bi = NT;
    for (int t = tid; t < NT; t += 256) {
        float v = mag[t];
        if (v > bv) { bv = v; bi = t; }
    }
    rv[tid] = bv; ri[tid] = bi;
    __syncthreads();
    for (int s = 128; s > 0; s >>= 1) {
        if (tid < s) {
            float v2 = rv[tid + s]; int i2 = ri[tid + s];
            if (v2 > rv[tid] || (v2 == rv[tid] && i2 < ri[tid])) { rv[tid] = v2; ri[tid] = i2; }
        }
        __syncthreads();
    }
    if (tid == 0) {
        const int mid = ri[0];
        int lo = mid - 20; if (lo < 0) lo = 0;
        int hi = mid + 20; if (hi > NT) hi = NT;
        float s = 0.0f;
        for (int t = lo; t < hi; ++t) s += mag[t];   // pulse[:, FC_INDEX]
        mid_out[n]   = mid;
        sig_out[n]   = s;
        noise_sum[n] = 0.0f;   // init accumulator for kernel B
    }
}

// ---------------- Kernel B: noise_sum[n] = sum_{c, f in mask, t} |x|
__global__ void kB_noise(const float* __restrict__ x, float* __restrict__ noise_sum) {
    const int n = blockIdx.y;                  // 0..31
    const int per_n = 2 * NOISE_F * NT4;       // 519600 float4s
    const size_t base = (size_t)n * 2 * PLANE4; // float4 units
    const float4* __restrict__ x4 = (const float4*)x;

    float part = 0.0f;
    for (int i = blockIdx.x * 256 + threadIdx.x; i < per_n; i += gridDim.x * 256) {
        int c   = i / (NOISE_F * NT4);
        int rem = i - c * (NOISE_F * NT4);
        int fj  = rem / NT4;
        int t4  = rem - fj * NT4;
        int f   = (fj < NOISE_LO) ? fj : fj + (NOISE_HI - NOISE_LO);  // skip 999..1399
        float4 v = x4[base + (size_t)(c * NF + f) * NT4 + t4];
        part += fabsf(v.x) + fabsf(v.y) + fabsf(v.z) + fabsf(v.w);
    }
    // wave64 reduce, then cross-wave via LDS
    for (int off = 32; off > 0; off >>= 1) part += __shfl_down(part, off, 64);
    __shared__ float ws[4];
    const int lane = threadIdx.x & 63, wv = threadIdx.x >> 6;
    if (lane == 0) ws[wv] = part;
    __syncthreads();
    if (threadIdx.x == 0)
        atomicAdd(&noise_sum[n], ws[0] + ws[1] + ws[2] + ws[3]);
}

// ---------------- Kernel C: snr -> hb; build bitmasks Fm[f], Tm[t]
__global__ void kC_masks(const int* __restrict__ mid_in, const float* __restrict__ sig_in,
                         const float* __restrict__ noise_sum,
                         unsigned* __restrict__ Fm, unsigned* __restrict__ Tm) {
    __shared__ int s_hb[N_BATCH];
    __shared__ int s_mid[N_BATCH];
    const int tid = threadIdx.x;
    if (tid < N_BATCH) {
        float noise = noise_sum[tid] / (float)NOISE_CNT;
        float d = sig_in[tid] - noise;
        float snr = 10.0f * log10f((d * d) / (noise * noise));
        int hb = (int)truncf(6.0f * (snr - 48.0f) + 27.0f);
        if (hb < 8) hb = 8;
        s_hb[tid]  = hb;
        s_mid[tid] = mid_in[tid];
    }
    __syncthreads();
    for (int f = tid; f < NF; f += 256) {
        unsigned w = 0;
        #pragma unroll
        for (int n = 0; n < N_BATCH; ++n)
            if (f >= FC_IDX - s_hb[n] && f < FC_IDX + s_hb[n]) w |= 1u << n;
        Fm[f] = w;
    }
    for (int t = tid; t < NT; t += 256) {
        unsigned w = 0;
        #pragma unroll
        for (int n = 0; n < N_BATCH; ++n)
            if (t >= s_mid[n] - 8 && t < s_mid[n] + 8) w |= 1u << n;
        Tm[t] = w;
    }
}

// ---------------- Kernel D: out = keep(f,t) ? x : 0   (float4; skip x read if row dead)
__global__ void kD_write(const float* __restrict__ x, float* __restrict__ out,
                         const unsigned* __restrict__ Fm, const unsigned* __restrict__ Tm) {
    const int nc = blockIdx.y;                           // 0..63  (n*2+c)
    const int i  = blockIdx.x * 256 + threadIdx.x;       // float4 idx within plane
    if (i >= PLANE4) return;
    const int f  = i / NT4;
    const int t4 = (i - f * NT4) * 4;
    const size_t idx = (size_t)nc * PLANE4 + i;
    float4 r = make_float4(0.f, 0.f, 0.f, 0.f);
    const unsigned fm = Fm[f];
    if (fm != 0) {
        float4 v = ((const float4*)x)[idx];
        if (fm & Tm[t4 + 0]) r.x = v.x;
        if (fm & Tm[t4 + 1]) r.y = v.y;
        if (fm & Tm[t4 + 2]) r.z = v.z;
        if (fm & Tm[t4 + 3]) r.w = v.w;
    }
    ((float4*)out)[idx] = r;
}

extern "C" void kernel_launch(void* const* d_in, const int* in_sizes, int n_in,
                              void* d_out, int out_size, void* d_ws, size_t ws_size,
                              hipStream_t stream) {
    const float* x = (const float*)d_in[0];
    float* out = (float*)d_out;

    // workspace layout (bytes): mid[32]i32 @0, sig[32]f32 @128, noise[32]f32 @256,
    // Fm[2999]u32 @384, Tm[400]u32 @12380
    char* ws = (char*)d_ws;
    int*      mid   = (int*)(ws + 0);
    float*    sig   = (float*)(ws + 128);
    float*    noise = (float*)(ws + 256);
    unsigned* Fm    = (unsigned*)(ws + 384);
    unsigned* Tm    = (unsigned*)(ws + 384 + NF * 4);

    kA_fcrow<<<N_BATCH, 256, 0, stream>>>(x, mid, sig, noise);
    kB_noise<<<dim3(128, N_BATCH), 256, 0, stream>>>(x, noise);
    kC_masks<<<1, 256, 0, stream>>>(mid, sig, noise, Fm, Tm);
    kD_write<<<dim3((PLANE4 + 255) / 256, 64), 256, 0, stream>>>(x, out, Fm, Tm);
}

// Round 2
// 486.373 us; speedup vs baseline: 1.0695x; 1.0695x over previous
//
#include <hip/hip_runtime.h>
#include <math.h>

// x: (8,4,2,2999,400) f32 -> N=32 batches, C=2, F=2999, T=400
// FC_INDEX=1199; noise freqs: f<999 || f>=1400 (2598 rows)
#define N_BATCH 32
#define NF 2999
#define NT 400
#define NT4 100                    // float4s per t-row
#define FC_IDX 1199
#define NOISE_LO 999
#define NOISE_HI 1400
#define NOISE_F 2598
#define NOISE_CNT (NOISE_F * NT)   // 1039200
#define PLANE4 (NF * NT4)          // 299900 float4s per (n,c) plane
#define NOISE_BLOCKS 128
#define SPAN_C (NOISE_F * NT4)     // 259800 float4s of noise per (n,c)
#define SPAN1 (NOISE_LO * NT4)     // 99900
#define GAP   ((NOISE_HI - NOISE_LO) * NT4)  // 40100

// ---- Kernel 1: fused noise partial-sums (blocks 0..127) + FC-row stats (block 128)
__global__ void k1_stats(const float* __restrict__ x, float* __restrict__ partials,
                         int* __restrict__ mid_out, float* __restrict__ sig_out) {
    const int n = blockIdx.y;
    const int tid = threadIdx.x;
    __shared__ float mag[NT];
    __shared__ float rv[256];
    __shared__ int   ri[256];

    if (blockIdx.x < NOISE_BLOCKS) {
        // ---- noise abs-sum over the two contiguous spans, no divisions ----
        const float4* __restrict__ x4 = (const float4*)x;
        const size_t base = (size_t)n * 2 * PLANE4;
        float part = 0.0f;
        const int stride = NOISE_BLOCKS * 256;
        for (int j = blockIdx.x * 256 + tid; j < 2 * SPAN_C; j += stride) {
            const int c   = (j >= SPAN_C) ? 1 : 0;
            const int k   = j - (c ? SPAN_C : 0);
            const int off = (k < SPAN1) ? k : k + GAP;   // skip f in [999,1400)
            const float4 v = x4[base + (size_t)c * PLANE4 + off];
            part += fabsf(v.x) + fabsf(v.y) + fabsf(v.z) + fabsf(v.w);
        }
        for (int o = 32; o > 0; o >>= 1) part += __shfl_down(part, o, 64);
        if ((tid & 63) == 0) rv[tid >> 6] = part;
        __syncthreads();
        if (tid == 0)
            partials[n * NOISE_BLOCKS + blockIdx.x] = rv[0] + rv[1] + rv[2] + rv[3];
    } else {
        // ---- FC row: mid (first-occurrence argmax) + sig (±20 window sum) ----
        const float* p0 = x + ((size_t)(n * 2 + 0) * NF + FC_IDX) * NT;
        const float* p1 = x + ((size_t)(n * 2 + 1) * NF + FC_IDX) * NT;
        for (int t = tid; t < NT; t += 256)
            mag[t] = fabsf(p0[t]) + fabsf(p1[t]);
        __syncthreads();
        float bv = -1.0f; int bi = NT;
        for (int t = tid; t < NT; t += 256) {
            float v = mag[t];
            if (v > bv) { bv = v; bi = t; }
        }
        rv[tid] = bv; ri[tid] = bi;
        __syncthreads();
        for (int s = 128; s > 0; s >>= 1) {
            if (tid < s) {
                float v2 = rv[tid + s]; int i2 = ri[tid + s];
                if (v2 > rv[tid] || (v2 == rv[tid] && i2 < ri[tid])) { rv[tid] = v2; ri[tid] = i2; }
            }
            __syncthreads();
        }
        if (tid == 0) {
            const int mid = ri[0];
            int lo = mid - 20; if (lo < 0) lo = 0;
            int hi = mid + 20; if (hi > NT) hi = NT;
            float s = 0.0f;
            for (int t = lo; t < hi; ++t) s += mag[t];
            mid_out[n] = mid;
            sig_out[n] = s;
        }
    }
}

// ---- Kernel 2: reduce partials -> noise; snr -> hb; build bitmasks Fm, Tm
__global__ void k2_masks(const float* __restrict__ partials, const int* __restrict__ mid_in,
                         const float* __restrict__ sig_in,
                         unsigned* __restrict__ Fm, unsigned* __restrict__ Tm) {
    __shared__ float s[256];
    __shared__ int s_hb[N_BATCH];
    __shared__ int s_mid[N_BATCH];
    const int tid = threadIdx.x;
    // 32 n x 128 partials: thread tid sums floats [tid*16, tid*16+16)
    const float4* p4 = (const float4*)partials;
    float acc = 0.0f;
    #pragma unroll
    for (int q = 0; q < 4; ++q) {
        float4 v = p4[tid * 4 + q];
        acc += v.x + v.y + v.z + v.w;
    }
    s[tid] = acc;
    __syncthreads();
    if (tid < N_BATCH) {
        float ns = 0.0f;
        #pragma unroll
        for (int q = 0; q < 8; ++q) ns += s[tid * 8 + q];
        float noise = ns / (float)NOISE_CNT;
        float d = sig_in[tid] - noise;
        float snr = 10.0f * log10f((d * d) / (noise * noise));
        int hb = (int)truncf(6.0f * (snr - 48.0f) + 27.0f);
        s_hb[tid]  = hb < 8 ? 8 : hb;
        s_mid[tid] = mid_in[tid];
    }
    __syncthreads();
    for (int f = tid; f < NF; f += 256) {
        unsigned w = 0;
        #pragma unroll
        for (int n = 0; n < N_BATCH; ++n)
            if (f >= FC_IDX - s_hb[n] && f < FC_IDX + s_hb[n]) w |= 1u << n;
        Fm[f] = w;
    }
    for (int t = tid; t < NT; t += 256) {
        unsigned w = 0;
        #pragma unroll
        for (int n = 0; n < N_BATCH; ++n)
            if (t >= s_mid[n] - 8 && t < s_mid[n] + 8) w |= 1u << n;
        Tm[t] = w;
    }
}

// ---- Kernel 3: out = keep(f,t) ? x : 0  (2 float4/thread; skip x read on dead rows)
__global__ void k3_write(const float* __restrict__ x, float* __restrict__ out,
                         const unsigned* __restrict__ Fm, const unsigned* __restrict__ Tm) {
    const int nc = blockIdx.y;                 // 0..63
    const size_t pbase = (size_t)nc * PLANE4;
    int i = blockIdx.x * 512 + threadIdx.x;
    #pragma unroll
    for (int r = 0; r < 2; ++r, i += 256) {
        if (i < PLANE4) {
            const int f  = i / NT4;            // div by const 100 -> magic mul
            const int t4 = (i - f * NT4) * 4;
            float4 rv = make_float4(0.f, 0.f, 0.f, 0.f);
            const unsigned fm = Fm[f];
            if (fm != 0) {
                const float4 v = ((const float4*)x)[pbase + i];
                const uint4 tm = *(const uint4*)(Tm + t4);
                if (fm & tm.x) rv.x = v.x;
                if (fm & tm.y) rv.y = v.y;
                if (fm & tm.z) rv.z = v.z;
                if (fm & tm.w) rv.w = v.w;
            }
            ((float4*)out)[pbase + i] = rv;
        }
    }
}

extern "C" void kernel_launch(void* const* d_in, const int* in_sizes, int n_in,
                              void* d_out, int out_size, void* d_ws, size_t ws_size,
                              hipStream_t stream) {
    const float* x = (const float*)d_in[0];
    float* out = (float*)d_out;

    // ws layout (bytes): partials[32*128]f32 @0 (16384), mid[32]i32 @16384,
    // sig[32]f32 @16512, Fm[2999]u32 @16640 (pad to 12000B), Tm[400]u32 @28640
    char* ws = (char*)d_ws;
    float*    partials = (float*)(ws + 0);
    int*      mid      = (int*)(ws + 16384);
    float*    sig      = (float*)(ws + 16512);
    unsigned* Fm       = (unsigned*)(ws + 16640);
    unsigned* Tm       = (unsigned*)(ws + 28640);

    k1_stats<<<dim3(NOISE_BLOCKS + 1, N_BATCH), 256, 0, stream>>>(x, partials, mid, sig);
    k2_masks<<<1, 256, 0, stream>>>(partials, mid, sig, Fm, Tm);
    k3_write<<<dim3((PLANE4 + 511) / 512, 64), 256, 0, stream>>>(x, out, Fm, Tm);
}